// Round 1
// baseline (1027.371 us; speedup 1.0000x reference)
//
#include <hip/hip_runtime.h>
#include <stdint.h>

#define B_ 2
#define S_ 1024
#define HID 2048
#define NK 16
#define NV 32
#define DK_ 128
#define DV_ 128
#define QKVZ_N 12288
#define TOK (B_*S_)

typedef unsigned short u16;
typedef __bf16 bf16x8 __attribute__((ext_vector_type(8)));
typedef float f32x4 __attribute__((ext_vector_type(4)));
typedef unsigned short u16x8 __attribute__((ext_vector_type(8)));
typedef unsigned short u16x4 __attribute__((ext_vector_type(4)));

__device__ __forceinline__ float bf2f(u16 u) {
    return __builtin_bit_cast(float, (unsigned)u << 16);
}
__device__ __forceinline__ u16 f2bf(float f) {
    unsigned u = __builtin_bit_cast(unsigned, f);
    u += 0x7fff + ((u >> 16) & 1);
    return (u16)(u >> 16);
}

// ---------------- fp32 -> bf16 elementwise ----------------
__global__ void k_cvt_bf16(const float* __restrict__ in, u16* __restrict__ out, int n) {
    int i = (blockIdx.x * blockDim.x + threadIdx.x) * 4;
    if (i >= n) return;
    float4 v = *(const float4*)(in + i);
    u16x4 o = { f2bf(v.x), f2bf(v.y), f2bf(v.z), f2bf(v.w) };
    *(u16x4*)(out + i) = o;
}

// ---------------- fp32 (R,C) -> bf16 (C,R) tiled transpose ----------------
__global__ void k_transpose(const float* __restrict__ in, u16* __restrict__ out, int R, int C) {
    __shared__ float tile[32][33];
    int c0 = blockIdx.x * 32, r0 = blockIdx.y * 32;
    int tx = threadIdx.x, ty = threadIdx.y;  // (32,8)
#pragma unroll
    for (int i = 0; i < 4; i++)
        tile[ty + i * 8][tx] = in[(size_t)(r0 + ty + i * 8) * C + c0 + tx];
    __syncthreads();
#pragma unroll
    for (int i = 0; i < 4; i++)
        out[(size_t)(c0 + ty + i * 8) * R + r0 + tx] = f2bf(tile[tx][ty + i * 8]);
}

// ---------------- bf16 GEMM: C(M,N) = A(M,K) * Bt(N,K)^T ----------------
// 128x128 tile, BK=32, 4 waves, 4x4 16x16x32 fragments per wave.
template <int OUT_BF16>
__global__ __launch_bounds__(256) void k_gemm(const u16* __restrict__ A, const u16* __restrict__ Bt,
                                              void* __restrict__ Cv, int K, int ldc) {
    __shared__ u16 As[128 * 40];  // row stride 40 bf16 = 80B (16B-aligned, ~2-way banks)
    __shared__ u16 Bs[128 * 40];
    int tid = threadIdx.x;
    int bm = blockIdx.y, bn = blockIdx.x;
    int wid = tid >> 6, lane = tid & 63;
    int wm = wid >> 1, wn = wid & 1;
    int l15 = lane & 15, lg = lane >> 4;
    int srow = tid >> 2, schunk = (tid & 3) * 8;
    const u16* Ag = A + (size_t)(bm * 128 + srow) * K + schunk;
    const u16* Bg = Bt + (size_t)(bn * 128 + srow) * K + schunk;
    f32x4 acc[4][4] = {};
    for (int k0 = 0; k0 < K; k0 += 32) {
        u16x8 a0 = *(const u16x8*)(Ag + k0);
        u16x8 a1 = *(const u16x8*)(Ag + (size_t)64 * K + k0);
        u16x8 b0 = *(const u16x8*)(Bg + k0);
        u16x8 b1 = *(const u16x8*)(Bg + (size_t)64 * K + k0);
        __syncthreads();
        *(u16x8*)&As[srow * 40 + schunk] = a0;
        *(u16x8*)&As[(srow + 64) * 40 + schunk] = a1;
        *(u16x8*)&Bs[srow * 40 + schunk] = b0;
        *(u16x8*)&Bs[(srow + 64) * 40 + schunk] = b1;
        __syncthreads();
        bf16x8 af[4], bf[4];
#pragma unroll
        for (int mi = 0; mi < 4; mi++)
            af[mi] = __builtin_bit_cast(bf16x8, *(const u16x8*)&As[(wm * 64 + mi * 16 + l15) * 40 + lg * 8]);
#pragma unroll
        for (int ni = 0; ni < 4; ni++)
            bf[ni] = __builtin_bit_cast(bf16x8, *(const u16x8*)&Bs[(wn * 64 + ni * 16 + l15) * 40 + lg * 8]);
#pragma unroll
        for (int mi = 0; mi < 4; mi++)
#pragma unroll
            for (int ni = 0; ni < 4; ni++)
                acc[mi][ni] = __builtin_amdgcn_mfma_f32_16x16x32_bf16(af[mi], bf[ni], acc[mi][ni], 0, 0, 0);
    }
#pragma unroll
    for (int mi = 0; mi < 4; mi++) {
        int gr0 = bm * 128 + wm * 64 + mi * 16 + lg * 4;
#pragma unroll
        for (int ni = 0; ni < 4; ni++) {
            int gc = bn * 128 + wn * 64 + ni * 16 + l15;
#pragma unroll
            for (int r = 0; r < 4; r++) {
                if (OUT_BF16)
                    ((u16*)Cv)[(size_t)(gr0 + r) * ldc + gc] = f2bf(acc[mi][ni][r]);
                else
                    ((float*)Cv)[(size_t)(gr0 + r) * ldc + gc] = acc[mi][ni][r];
            }
        }
    }
}

// ---------------- ba = hidden @ W_ba (fp32, N=64) ----------------
__global__ void k_ba(const float* __restrict__ hid, const float* __restrict__ Wba, float* __restrict__ ba) {
    int token = blockIdx.x;
    int c = threadIdx.x;  // 64
    const float* h = hid + (size_t)token * HID;
    const float* w = Wba + c;
    float acc = 0.f;
    for (int k = 0; k < HID; k += 4) {
        float4 hv = *(const float4*)(h + k);
        acc += hv.x * w[(size_t)k * 64] + hv.y * w[(size_t)(k + 1) * 64] +
               hv.z * w[(size_t)(k + 2) * 64] + hv.w * w[(size_t)(k + 3) * 64];
    }
    ba[(size_t)token * 64 + c] = acc;
}

// ---------------- causal depthwise conv4 + silu + l2norm + g/beta ----------------
__global__ __launch_bounds__(256) void k_conv(const u16* __restrict__ qkvz, const float* __restrict__ ba,
                                              const float* __restrict__ cw, const float* __restrict__ A_log,
                                              const float* __restrict__ dt_bias, float* __restrict__ qn,
                                              float* __restrict__ kn, float* __restrict__ vout,
                                              float* __restrict__ g, float* __restrict__ beta) {
    __shared__ float sm[4096];  // conv+silu results for q (0..2047) and k (2048..4095)
    int token = blockIdx.x;
    int t = token & (S_ - 1);
    int tid = threadIdx.x;
    const u16* row3 = qkvz + (size_t)token * QKVZ_N;
#pragma unroll
    for (int i = 0; i < 32; i++) {
        int c = tid + i * 256;  // mixed channel 0..8191 (q 2048 | k 2048 | v 4096)
        int col;
        if (c < 2048) col = (c >> 7) * 768 + (c & 127);
        else if (c < 4096) col = ((c - 2048) >> 7) * 768 + 128 + (c & 127);
        else {
            int cc = c - 4096;
            col = (cc >> 8) * 768 + 256 + ((cc >> 7) & 1) * 128 + (cc & 127);
        }
        float4 w = *(const float4*)(cw + c * 4);
        float x3 = bf2f(row3[col]);
        float x2 = (t >= 1) ? bf2f(row3[col - QKVZ_N]) : 0.f;
        float x1 = (t >= 2) ? bf2f(row3[col - 2 * QKVZ_N]) : 0.f;
        float x0 = (t >= 3) ? bf2f(row3[col - 3 * QKVZ_N]) : 0.f;
        float s = w.x * x0 + w.y * x1 + w.z * x2 + w.w * x3;
        s = s / (1.f + __expf(-s));  // silu
        if (c < 4096) sm[c] = s;
        else vout[(size_t)token * 4096 + (c - 4096)] = s;
    }
    __syncthreads();
    int grp = tid >> 3, l8 = tid & 7;  // grp 0..15: q heads; 16..31: k heads
    float vals[16];
    float ss = 0.f;
    const float* sp = sm + grp * 128 + l8 * 16;
#pragma unroll
    for (int i = 0; i < 16; i++) { vals[i] = sp[i]; ss += vals[i] * vals[i]; }
    ss += __shfl_xor(ss, 1); ss += __shfl_xor(ss, 2); ss += __shfl_xor(ss, 4);
    float scale = rsqrtf(ss + 1e-6f);
    if (grp < 16) scale *= 0.08838834764831845f;  // DK^-0.5
    float* op = (grp < 16 ? qn : kn) + (size_t)token * 2048 + (grp & 15) * 128 + l8 * 16;
#pragma unroll
    for (int i = 0; i < 16; i++) op[i] = vals[i] * scale;
    if (tid < 32) {
        int hv = tid;
        float bval = ba[(size_t)token * 64 + (hv >> 1) * 4 + (hv & 1)];
        float aval = ba[(size_t)token * 64 + (hv >> 1) * 4 + 2 + (hv & 1)];
        float x = aval + dt_bias[hv];
        float sp2 = (x > 20.f) ? x : log1pf(__expf(x));
        g[(size_t)token * 32 + hv] = -__expf(A_log[hv]) * sp2;
        beta[(size_t)token * 32 + hv] = 1.f / (1.f + __expf(-bval));
    }
}

// ---------------- sequential delta-rule scan ----------------
// grid = 64 (b,hv) * 4 v-splits; block = 512. thread: vidx = split*32 + tid>>4,
// owns 8 state rows (rq = tid&15, rows rq*8..+7). k-reductions via shfl over 16 lanes.
__global__ __launch_bounds__(512) void k_scan(const float* __restrict__ qn, const float* __restrict__ kn,
                                              const float* __restrict__ v, const float* __restrict__ g,
                                              const float* __restrict__ beta, float* __restrict__ core) {
    int bid = blockIdx.x;
    int bh = bid >> 2, vs = bid & 3;
    int b = bh >> 5, hv = bh & 31, hk = hv >> 1;
    int tid = threadIdx.x;
    int vloc = tid >> 4, rq = tid & 15;
    int vidx = vs * 32 + vloc;
    const float* kp = kn + ((size_t)b * S_ * NK + hk) * DK_ + rq * 8;
    const float* qp = qn + ((size_t)b * S_ * NK + hk) * DK_ + rq * 8;
    const float* vp = v + ((size_t)b * S_ * NV + hv) * DV_ + vidx;
    const float* gp = g + (size_t)b * S_ * NV + hv;
    const float* bp = beta + (size_t)b * S_ * NV + hv;
    float* cp = core + ((size_t)b * S_ * NV + hv) * DV_ + vidx;
    float st[8] = {0, 0, 0, 0, 0, 0, 0, 0};
    float4 kc0 = *(const float4*)kp, kc1 = *(const float4*)(kp + 4);
    float4 qc0 = *(const float4*)qp, qc1 = *(const float4*)(qp + 4);
    float vc = *vp, gc = *gp, bc = *bp;
    for (int t = 0; t < S_; ++t) {
        int tn = (t < S_ - 1) ? t + 1 : t;  // prefetch next step (clamped)
        float4 ka0 = *(const float4*)(kp + (size_t)tn * NK * DK_);
        float4 ka1 = *(const float4*)(kp + (size_t)tn * NK * DK_ + 4);
        float4 qa0 = *(const float4*)(qp + (size_t)tn * NK * DK_);
        float4 qa1 = *(const float4*)(qp + (size_t)tn * NK * DK_ + 4);
        float va = vp[(size_t)tn * NV * DV_];
        float ga = gp[(size_t)tn * NV];
        float bb2 = bp[(size_t)tn * NV];

        float eg = __expf(gc);
        float kv[8] = {kc0.x, kc0.y, kc0.z, kc0.w, kc1.x, kc1.y, kc1.z, kc1.w};
        float qv[8] = {qc0.x, qc0.y, qc0.z, qc0.w, qc1.x, qc1.y, qc1.z, qc1.w};
        float pr = 0.f;
#pragma unroll
        for (int i = 0; i < 8; i++) { st[i] *= eg; pr += kv[i] * st[i]; }
        pr += __shfl_xor(pr, 1); pr += __shfl_xor(pr, 2);
        pr += __shfl_xor(pr, 4); pr += __shfl_xor(pr, 8);
        float delta = (vc - pr) * bc;
        float ou = 0.f;
#pragma unroll
        for (int i = 0; i < 8; i++) { st[i] += kv[i] * delta; ou += qv[i] * st[i]; }
        ou += __shfl_xor(ou, 1); ou += __shfl_xor(ou, 2);
        ou += __shfl_xor(ou, 4); ou += __shfl_xor(ou, 8);
        if (rq == 0) cp[(size_t)t * NV * DV_] = ou;
        kc0 = ka0; kc1 = ka1; qc0 = qa0; qc1 = qa1; vc = va; gc = ga; bc = bb2;
    }
}

// ---------------- RMS-norm * norm_weight * silu(z) -> bf16 ----------------
__global__ __launch_bounds__(256) void k_gate(const float* __restrict__ core, const u16* __restrict__ qkvz,
                                              const float* __restrict__ nw, u16* __restrict__ gated) {
    int token = blockIdx.x, tid = threadIdx.x;
    int grp = tid >> 3, l8 = tid & 7;  // grp = hv
    const float* cp = core + ((size_t)token * NV + grp) * DV_ + l8 * 16;
    float vals[16];
    float ss = 0.f;
#pragma unroll
    for (int i = 0; i < 16; i++) { vals[i] = cp[i]; ss += vals[i] * vals[i]; }
    ss += __shfl_xor(ss, 1); ss += __shfl_xor(ss, 2); ss += __shfl_xor(ss, 4);
    float rms = rsqrtf(ss * (1.0f / DV_) + 1e-6f);
    const u16* zp = qkvz + (size_t)token * QKVZ_N + (grp >> 1) * 768 + 512 + (grp & 1) * 128 + l8 * 16;
    u16* op = gated + ((size_t)token * NV + grp) * DV_ + l8 * 16;
#pragma unroll
    for (int i = 0; i < 16; i++) {
        float z = bf2f(zp[i]);
        float sz = z / (1.f + __expf(-z));
        op[i] = f2bf(vals[i] * rms * nw[l8 * 16 + i] * sz);
    }
}

extern "C" void kernel_launch(void* const* d_in, const int* in_sizes, int n_in,
                              void* d_out, int out_size, void* d_ws, size_t ws_size,
                              hipStream_t stream) {
    const float* hidden = (const float*)d_in[0];
    const float* Wqkvz = (const float*)d_in[1];
    const float* Wba = (const float*)d_in[2];
    const float* convw = (const float*)d_in[3];
    const float* A_log = (const float*)d_in[4];
    const float* dt_bias = (const float*)d_in[5];
    const float* norm_w = (const float*)d_in[6];
    const float* Wout = (const float*)d_in[7];

    char* ws = (char*)d_ws;
    size_t off = 0;
    auto alloc = [&](size_t bytes) -> void* {
        void* p = ws + off;
        off += (bytes + 255) & ~(size_t)255;
        return p;
    };
    u16* hiddenB = (u16*)alloc((size_t)TOK * HID * 2);
    u16* WqT = (u16*)alloc((size_t)QKVZ_N * HID * 2);
    u16* WoT = (u16*)alloc((size_t)HID * 4096 * 2);
    u16* qkvz = (u16*)alloc((size_t)TOK * QKVZ_N * 2);
    float* ba = (float*)alloc((size_t)TOK * 64 * 4);
    float* qn = (float*)alloc((size_t)TOK * 2048 * 4);
    float* kn = (float*)alloc((size_t)TOK * 2048 * 4);
    float* vb = (float*)alloc((size_t)TOK * 4096 * 4);
    float* gb = (float*)alloc((size_t)TOK * 32 * 4);
    float* bb = (float*)alloc((size_t)TOK * 32 * 4);
    float* core = (float*)alloc((size_t)TOK * 4096 * 4);
    u16* gated = (u16*)alloc((size_t)TOK * 4096 * 2);

    k_cvt_bf16<<<4096, 256, 0, stream>>>(hidden, hiddenB, TOK * HID);
    k_transpose<<<dim3(QKVZ_N / 32, HID / 32), dim3(32, 8), 0, stream>>>(Wqkvz, WqT, HID, QKVZ_N);
    k_transpose<<<dim3(HID / 32, 4096 / 32), dim3(32, 8), 0, stream>>>(Wout, WoT, 4096, HID);
    k_gemm<1><<<dim3(QKVZ_N / 128, TOK / 128), 256, 0, stream>>>(hiddenB, WqT, qkvz, HID, QKVZ_N);
    k_ba<<<TOK, 64, 0, stream>>>(hidden, Wba, ba);
    k_conv<<<TOK, 256, 0, stream>>>(qkvz, ba, convw, A_log, dt_bias, qn, kn, vb, gb, bb);
    k_scan<<<256, 512, 0, stream>>>(qn, kn, vb, gb, bb, core);
    k_gate<<<TOK, 256, 0, stream>>>(core, qkvz, norm_w, gated);
    k_gemm<0><<<dim3(HID / 128, TOK / 128), 256, 0, stream>>>(gated, WoT, d_out, 4096, HID);
}

// Round 2
// 744.227 us; speedup vs baseline: 1.3805x; 1.3805x over previous
//
#include <hip/hip_runtime.h>
#include <stdint.h>

#define B_ 2
#define S_ 1024
#define HID 2048
#define NK 16
#define NV 32
#define DK_ 128
#define DV_ 128
#define QKVZ_N 12288
#define TOK (B_*S_)

typedef unsigned short u16;
typedef __bf16 bf16x8 __attribute__((ext_vector_type(8)));
typedef float f32x4 __attribute__((ext_vector_type(4)));
typedef unsigned short u16x8 __attribute__((ext_vector_type(8)));
typedef unsigned short u16x4 __attribute__((ext_vector_type(4)));

__device__ __forceinline__ float bf2f(u16 u) {
    return __builtin_bit_cast(float, (unsigned)u << 16);
}
__device__ __forceinline__ u16 f2bf(float f) {
    unsigned u = __builtin_bit_cast(unsigned, f);
    u += 0x7fff + ((u >> 16) & 1);
    return (u16)(u >> 16);
}

// 16-lane butterfly sum via DPP (full-rate VALU, no LDS routing).
template <int CTRL>
__device__ __forceinline__ float dpp_add(float x) {
    int yi = __builtin_amdgcn_update_dpp(0, __builtin_bit_cast(int, x), CTRL, 0xF, 0xF, true);
    return x + __builtin_bit_cast(float, yi);
}
__device__ __forceinline__ float sum16(float x) {
    x = dpp_add<0xB1>(x);   // quad_perm [1,0,3,2]  (xor 1)
    x = dpp_add<0x4E>(x);   // quad_perm [2,3,0,1]  (xor 2)
    x = dpp_add<0x141>(x);  // row_half_mirror      (xor 7 ~ xor 4)
    x = dpp_add<0x140>(x);  // row_mirror           (xor 15 ~ xor 8)
    return x;
}

// ---------------- fp32 -> bf16 elementwise ----------------
__global__ void k_cvt_bf16(const float* __restrict__ in, u16* __restrict__ out, int n) {
    int i = (blockIdx.x * blockDim.x + threadIdx.x) * 4;
    if (i >= n) return;
    float4 v = *(const float4*)(in + i);
    u16x4 o = { f2bf(v.x), f2bf(v.y), f2bf(v.z), f2bf(v.w) };
    *(u16x4*)(out + i) = o;
}

// ---------------- fp32 (R,C) -> bf16 (C,R) tiled transpose ----------------
__global__ void k_transpose(const float* __restrict__ in, u16* __restrict__ out, int R, int C) {
    __shared__ float tile[32][33];
    int c0 = blockIdx.x * 32, r0 = blockIdx.y * 32;
    int tx = threadIdx.x, ty = threadIdx.y;  // (32,8)
#pragma unroll
    for (int i = 0; i < 4; i++)
        tile[ty + i * 8][tx] = in[(size_t)(r0 + ty + i * 8) * C + c0 + tx];
    __syncthreads();
#pragma unroll
    for (int i = 0; i < 4; i++)
        out[(size_t)(c0 + ty + i * 8) * R + r0 + tx] = f2bf(tile[tx][ty + i * 8]);
}

// ---------------- bf16 GEMM: C(M,N) = A(M,K) * Bt(N,K)^T ----------------
template <int OUT_BF16>
__global__ __launch_bounds__(256) void k_gemm(const u16* __restrict__ A, const u16* __restrict__ Bt,
                                              void* __restrict__ Cv, int K, int ldc) {
    __shared__ u16 As[128 * 40];
    __shared__ u16 Bs[128 * 40];
    int tid = threadIdx.x;
    int bm = blockIdx.y, bn = blockIdx.x;
    int wid = tid >> 6, lane = tid & 63;
    int wm = wid >> 1, wn = wid & 1;
    int l15 = lane & 15, lg = lane >> 4;
    int srow = tid >> 2, schunk = (tid & 3) * 8;
    const u16* Ag = A + (size_t)(bm * 128 + srow) * K + schunk;
    const u16* Bg = Bt + (size_t)(bn * 128 + srow) * K + schunk;
    f32x4 acc[4][4] = {};
    for (int k0 = 0; k0 < K; k0 += 32) {
        u16x8 a0 = *(const u16x8*)(Ag + k0);
        u16x8 a1 = *(const u16x8*)(Ag + (size_t)64 * K + k0);
        u16x8 b0 = *(const u16x8*)(Bg + k0);
        u16x8 b1 = *(const u16x8*)(Bg + (size_t)64 * K + k0);
        __syncthreads();
        *(u16x8*)&As[srow * 40 + schunk] = a0;
        *(u16x8*)&As[(srow + 64) * 40 + schunk] = a1;
        *(u16x8*)&Bs[srow * 40 + schunk] = b0;
        *(u16x8*)&Bs[(srow + 64) * 40 + schunk] = b1;
        __syncthreads();
        bf16x8 af[4], bf[4];
#pragma unroll
        for (int mi = 0; mi < 4; mi++)
            af[mi] = __builtin_bit_cast(bf16x8, *(const u16x8*)&As[(wm * 64 + mi * 16 + l15) * 40 + lg * 8]);
#pragma unroll
        for (int ni = 0; ni < 4; ni++)
            bf[ni] = __builtin_bit_cast(bf16x8, *(const u16x8*)&Bs[(wn * 64 + ni * 16 + l15) * 40 + lg * 8]);
#pragma unroll
        for (int mi = 0; mi < 4; mi++)
#pragma unroll
            for (int ni = 0; ni < 4; ni++)
                acc[mi][ni] = __builtin_amdgcn_mfma_f32_16x16x32_bf16(af[mi], bf[ni], acc[mi][ni], 0, 0, 0);
    }
#pragma unroll
    for (int mi = 0; mi < 4; mi++) {
        int gr0 = bm * 128 + wm * 64 + mi * 16 + lg * 4;
#pragma unroll
        for (int ni = 0; ni < 4; ni++) {
            int gc = bn * 128 + wn * 64 + ni * 16 + l15;
#pragma unroll
            for (int r = 0; r < 4; r++) {
                if (OUT_BF16)
                    ((u16*)Cv)[(size_t)(gr0 + r) * ldc + gc] = f2bf(acc[mi][ni][r]);
                else
                    ((float*)Cv)[(size_t)(gr0 + r) * ldc + gc] = acc[mi][ni][r];
            }
        }
    }
}

// ---------------- ba = hidden @ W_ba (fp32, N=64) ----------------
__global__ void k_ba(const float* __restrict__ hid, const float* __restrict__ Wba, float* __restrict__ ba) {
    int token = blockIdx.x;
    int c = threadIdx.x;  // 64
    const float* h = hid + (size_t)token * HID;
    const float* w = Wba + c;
    float acc = 0.f;
    for (int k = 0; k < HID; k += 4) {
        float4 hv = *(const float4*)(h + k);
        acc += hv.x * w[(size_t)k * 64] + hv.y * w[(size_t)(k + 1) * 64] +
               hv.z * w[(size_t)(k + 2) * 64] + hv.w * w[(size_t)(k + 3) * 64];
    }
    ba[(size_t)token * 64 + c] = acc;
}

// ---------------- causal depthwise conv4 + silu + l2norm + exp(g)/beta ----------------
__global__ __launch_bounds__(256) void k_conv(const u16* __restrict__ qkvz, const float* __restrict__ ba,
                                              const float* __restrict__ cw, const float* __restrict__ A_log,
                                              const float* __restrict__ dt_bias, float* __restrict__ qn,
                                              float* __restrict__ kn, float* __restrict__ vout,
                                              float* __restrict__ g, float* __restrict__ beta) {
    __shared__ float sm[4096];
    int token = blockIdx.x;
    int t = token & (S_ - 1);
    int tid = threadIdx.x;
    const u16* row3 = qkvz + (size_t)token * QKVZ_N;
#pragma unroll
    for (int i = 0; i < 32; i++) {
        int c = tid + i * 256;
        int col;
        if (c < 2048) col = (c >> 7) * 768 + (c & 127);
        else if (c < 4096) col = ((c - 2048) >> 7) * 768 + 128 + (c & 127);
        else {
            int cc = c - 4096;
            col = (cc >> 8) * 768 + 256 + ((cc >> 7) & 1) * 128 + (cc & 127);
        }
        float4 w = *(const float4*)(cw + c * 4);
        float x3 = bf2f(row3[col]);
        float x2 = (t >= 1) ? bf2f(row3[col - QKVZ_N]) : 0.f;
        float x1 = (t >= 2) ? bf2f(row3[col - 2 * QKVZ_N]) : 0.f;
        float x0 = (t >= 3) ? bf2f(row3[col - 3 * QKVZ_N]) : 0.f;
        float s = w.x * x0 + w.y * x1 + w.z * x2 + w.w * x3;
        s = s / (1.f + __expf(-s));  // silu
        if (c < 4096) sm[c] = s;
        else vout[(size_t)token * 4096 + (c - 4096)] = s;
    }
    __syncthreads();
    int grp = tid >> 3, l8 = tid & 7;
    float vals[16];
    float ss = 0.f;
    const float* sp = sm + grp * 128 + l8 * 16;
#pragma unroll
    for (int i = 0; i < 16; i++) { vals[i] = sp[i]; ss += vals[i] * vals[i]; }
    ss += __shfl_xor(ss, 1); ss += __shfl_xor(ss, 2); ss += __shfl_xor(ss, 4);
    float scale = rsqrtf(ss + 1e-6f);
    if (grp < 16) scale *= 0.08838834764831845f;  // DK^-0.5
    float* op = (grp < 16 ? qn : kn) + (size_t)token * 2048 + (grp & 15) * 128 + l8 * 16;
#pragma unroll
    for (int i = 0; i < 16; i++) op[i] = vals[i] * scale;
    if (tid < 32) {
        int hv = tid;
        float bval = ba[(size_t)token * 64 + (hv >> 1) * 4 + (hv & 1)];
        float aval = ba[(size_t)token * 64 + (hv >> 1) * 4 + 2 + (hv & 1)];
        float x = aval + dt_bias[hv];
        float sp2 = (x > 20.f) ? x : log1pf(__expf(x));
        // store exp(g) directly so the scan has no transcendental on its chain
        g[(size_t)token * 32 + hv] = __expf(-__expf(A_log[hv]) * sp2);
        beta[(size_t)token * 32 + hv] = 1.f / (1.f + __expf(-bval));
    }
}

// ---------------- sequential delta-rule scan (DPP reduce + depth-4 prefetch) ----------------
// grid = 64 (b,hv) * 4 v-splits; block = 512. 16-lane group per v-column,
// each lane owns 8 state rows. eg_ holds exp(g).
__global__ __launch_bounds__(512) void k_scan(const float* __restrict__ qn, const float* __restrict__ kn,
                                              const float* __restrict__ v, const float* __restrict__ eg_,
                                              const float* __restrict__ beta, float* __restrict__ core) {
    int bid = blockIdx.x;
    int bh = bid >> 2, vs = bid & 3;
    int b = bh >> 5, hv = bh & 31, hk = hv >> 1;
    int tid = threadIdx.x;
    int vloc = tid >> 4, rq = tid & 15;
    int vidx = vs * 32 + vloc;
    const float* kp = kn + ((size_t)b * S_ * NK + hk) * DK_ + rq * 8;
    const float* qp = qn + ((size_t)b * S_ * NK + hk) * DK_ + rq * 8;
    const float* vp = v + ((size_t)b * S_ * NV + hv) * DV_ + vidx;
    const float* gp = eg_ + (size_t)b * S_ * NV + hv;
    const float* bp = beta + (size_t)b * S_ * NV + hv;
    float* cp = core + ((size_t)b * S_ * NV + hv) * DV_ + vidx;
    float st[8] = {0, 0, 0, 0, 0, 0, 0, 0};
    // depth-4 prefetch ring, statically indexed (unrolled)
    float4 ka[4][2], qa[4][2];
    float va[4], ga[4], bb_[4];
#pragma unroll
    for (int j = 0; j < 4; j++) {
        size_t o = (size_t)j * (NK * DK_);
        ka[j][0] = *(const float4*)(kp + o); ka[j][1] = *(const float4*)(kp + o + 4);
        qa[j][0] = *(const float4*)(qp + o); qa[j][1] = *(const float4*)(qp + o + 4);
        va[j] = vp[(size_t)j * (NV * DV_)];
        ga[j] = gp[(size_t)j * NV];
        bb_[j] = bp[(size_t)j * NV];
    }
    for (int t0 = 0; t0 < S_; t0 += 4) {
#pragma unroll
        for (int j = 0; j < 4; j++) {
            const int t = t0 + j;
            float kv[8] = {ka[j][0].x, ka[j][0].y, ka[j][0].z, ka[j][0].w,
                           ka[j][1].x, ka[j][1].y, ka[j][1].z, ka[j][1].w};
            float qv[8] = {qa[j][0].x, qa[j][0].y, qa[j][0].z, qa[j][0].w,
                           qa[j][1].x, qa[j][1].y, qa[j][1].z, qa[j][1].w};
            float vc = va[j], eg = ga[j], bc = bb_[j];
            int tn = t + 4; if (tn > S_ - 1) tn = S_ - 1;  // clamped prefetch (branch-free)
            {
                size_t o = (size_t)tn * (NK * DK_);
                ka[j][0] = *(const float4*)(kp + o); ka[j][1] = *(const float4*)(kp + o + 4);
                qa[j][0] = *(const float4*)(qp + o); qa[j][1] = *(const float4*)(qp + o + 4);
                va[j] = vp[(size_t)tn * (NV * DV_)];
                ga[j] = gp[(size_t)tn * NV];
                bb_[j] = bp[(size_t)tn * NV];
            }
            // pred = k·(S*eg) = eg*(k·S): keep the scale off the critical path
            float dk0 = 0.f, dk1 = 0.f;
#pragma unroll
            for (int i = 0; i < 4; i++) { dk0 += kv[i] * st[i]; dk1 += kv[i + 4] * st[i + 4]; }
            float dks = sum16(dk0 + dk1);
            float delta = (vc - eg * dks) * bc;
#pragma unroll
            for (int i = 0; i < 8; i++) st[i] = st[i] * eg + kv[i] * delta;
            float dq0 = 0.f, dq1 = 0.f;
#pragma unroll
            for (int i = 0; i < 4; i++) { dq0 += qv[i] * st[i]; dq1 += qv[i + 4] * st[i + 4]; }
            float dqs = sum16(dq0 + dq1);
            if (rq == 0) cp[(size_t)t * (NV * DV_)] = dqs;
        }
    }
}

// ---------------- RMS-norm * norm_weight * silu(z) -> bf16 ----------------
__global__ __launch_bounds__(256) void k_gate(const float* __restrict__ core, const u16* __restrict__ qkvz,
                                              const float* __restrict__ nw, u16* __restrict__ gated) {
    int token = blockIdx.x, tid = threadIdx.x;
    int grp = tid >> 3, l8 = tid & 7;
    const float* cp = core + ((size_t)token * NV + grp) * DV_ + l8 * 16;
    float vals[16];
    float ss = 0.f;
#pragma unroll
    for (int i = 0; i < 16; i++) { vals[i] = cp[i]; ss += vals[i] * vals[i]; }
    ss += __shfl_xor(ss, 1); ss += __shfl_xor(ss, 2); ss += __shfl_xor(ss, 4);
    float rms = rsqrtf(ss * (1.0f / DV_) + 1e-6f);
    const u16* zp = qkvz + (size_t)token * QKVZ_N + (grp >> 1) * 768 + 512 + (grp & 1) * 128 + l8 * 16;
    u16* op = gated + ((size_t)token * NV + grp) * DV_ + l8 * 16;
#pragma unroll
    for (int i = 0; i < 16; i++) {
        float z = bf2f(zp[i]);
        float sz = z / (1.f + __expf(-z));
        op[i] = f2bf(vals[i] * rms * nw[l8 * 16 + i] * sz);
    }
}

extern "C" void kernel_launch(void* const* d_in, const int* in_sizes, int n_in,
                              void* d_out, int out_size, void* d_ws, size_t ws_size,
                              hipStream_t stream) {
    const float* hidden = (const float*)d_in[0];
    const float* Wqkvz = (const float*)d_in[1];
    const float* Wba = (const float*)d_in[2];
    const float* convw = (const float*)d_in[3];
    const float* A_log = (const float*)d_in[4];
    const float* dt_bias = (const float*)d_in[5];
    const float* norm_w = (const float*)d_in[6];
    const float* Wout = (const float*)d_in[7];

    char* ws = (char*)d_ws;
    size_t off = 0;
    auto alloc = [&](size_t bytes) -> void* {
        void* p = ws + off;
        off += (bytes + 255) & ~(size_t)255;
        return p;
    };
    u16* hiddenB = (u16*)alloc((size_t)TOK * HID * 2);
    u16* WqT = (u16*)alloc((size_t)QKVZ_N * HID * 2);
    u16* WoT = (u16*)alloc((size_t)HID * 4096 * 2);
    u16* qkvz = (u16*)alloc((size_t)TOK * QKVZ_N * 2);
    float* ba = (float*)alloc((size_t)TOK * 64 * 4);
    float* qn = (float*)alloc((size_t)TOK * 2048 * 4);
    float* kn = (float*)alloc((size_t)TOK * 2048 * 4);
    float* vb = (float*)alloc((size_t)TOK * 4096 * 4);
    float* gb = (float*)alloc((size_t)TOK * 32 * 4);
    float* bb = (float*)alloc((size_t)TOK * 32 * 4);
    float* core = (float*)alloc((size_t)TOK * 4096 * 4);
    u16* gated = (u16*)alloc((size_t)TOK * 4096 * 2);

    k_cvt_bf16<<<4096, 256, 0, stream>>>(hidden, hiddenB, TOK * HID);
    k_transpose<<<dim3(QKVZ_N / 32, HID / 32), dim3(32, 8), 0, stream>>>(Wqkvz, WqT, HID, QKVZ_N);
    k_transpose<<<dim3(HID / 32, 4096 / 32), dim3(32, 8), 0, stream>>>(Wout, WoT, 4096, HID);
    k_gemm<1><<<dim3(QKVZ_N / 128, TOK / 128), 256, 0, stream>>>(hiddenB, WqT, qkvz, HID, QKVZ_N);
    k_ba<<<TOK, 64, 0, stream>>>(hidden, Wba, ba);
    k_conv<<<TOK, 256, 0, stream>>>(qkvz, ba, convw, A_log, dt_bias, qn, kn, vb, gb, bb);
    k_scan<<<256, 512, 0, stream>>>(qn, kn, vb, gb, bb, core);
    k_gate<<<TOK, 256, 0, stream>>>(core, qkvz, norm_w, gated);
    k_gemm<0><<<dim3(HID / 128, TOK / 128), 256, 0, stream>>>(gated, WoT, d_out, 4096, HID);
}

// Round 3
// 741.978 us; speedup vs baseline: 1.3846x; 1.0030x over previous
//
#include <hip/hip_runtime.h>
#include <stdint.h>

#define B_ 2
#define S_ 1024
#define HID 2048
#define NK 16
#define NV 32
#define DK_ 128
#define DV_ 128
#define QKVZ_N 12288
#define TOK (B_*S_)

typedef unsigned short u16;
typedef __bf16 bf16x8 __attribute__((ext_vector_type(8)));
typedef float f32x4 __attribute__((ext_vector_type(4)));
typedef float f32x2 __attribute__((ext_vector_type(2)));
typedef float f32x8v __attribute__((ext_vector_type(8)));
typedef unsigned short u16x8 __attribute__((ext_vector_type(8)));
typedef unsigned short u16x4 __attribute__((ext_vector_type(4)));

__device__ __forceinline__ float bf2f(u16 u) {
    return __builtin_bit_cast(float, (unsigned)u << 16);
}
__device__ __forceinline__ u16 f2bf(float f) {
    unsigned u = __builtin_bit_cast(unsigned, f);
    u += 0x7fff + ((u >> 16) & 1);
    return (u16)(u >> 16);
}

// 16-lane butterfly sum via DPP (full-rate VALU, no LDS routing).
template <int CTRL>
__device__ __forceinline__ float dpp_add(float x) {
    int yi = __builtin_amdgcn_update_dpp(0, __builtin_bit_cast(int, x), CTRL, 0xF, 0xF, true);
    return x + __builtin_bit_cast(float, yi);
}
__device__ __forceinline__ float sum16(float x) {
    x = dpp_add<0xB1>(x);   // quad_perm xor1
    x = dpp_add<0x4E>(x);   // quad_perm xor2
    x = dpp_add<0x141>(x);  // row_half_mirror
    x = dpp_add<0x140>(x);  // row_mirror
    return x;
}

// ---------------- fp32 -> bf16 elementwise ----------------
__global__ void k_cvt_bf16(const float* __restrict__ in, u16* __restrict__ out, int n) {
    int i = (blockIdx.x * blockDim.x + threadIdx.x) * 4;
    if (i >= n) return;
    float4 v = *(const float4*)(in + i);
    u16x4 o = { f2bf(v.x), f2bf(v.y), f2bf(v.z), f2bf(v.w) };
    *(u16x4*)(out + i) = o;
}

// ---------------- fp32 (R,C) -> bf16 (C,R) tiled transpose ----------------
__global__ void k_transpose(const float* __restrict__ in, u16* __restrict__ out, int R, int C) {
    __shared__ float tile[32][33];
    int c0 = blockIdx.x * 32, r0 = blockIdx.y * 32;
    int tx = threadIdx.x, ty = threadIdx.y;  // (32,8)
#pragma unroll
    for (int i = 0; i < 4; i++)
        tile[ty + i * 8][tx] = in[(size_t)(r0 + ty + i * 8) * C + c0 + tx];
    __syncthreads();
#pragma unroll
    for (int i = 0; i < 4; i++)
        out[(size_t)(c0 + ty + i * 8) * R + r0 + tx] = f2bf(tile[tx][ty + i * 8]);
}

// ---------------- bf16 GEMM: C(M,N) = A(M,K) * Bt(N,K)^T ----------------
template <int OUT_BF16>
__global__ __launch_bounds__(256) void k_gemm(const u16* __restrict__ A, const u16* __restrict__ Bt,
                                              void* __restrict__ Cv, int K, int ldc) {
    __shared__ u16 As[128 * 40];
    __shared__ u16 Bs[128 * 40];
    int tid = threadIdx.x;
    int bm = blockIdx.y, bn = blockIdx.x;
    int wid = tid >> 6, lane = tid & 63;
    int wm = wid >> 1, wn = wid & 1;
    int l15 = lane & 15, lg = lane >> 4;
    int srow = tid >> 2, schunk = (tid & 3) * 8;
    const u16* Ag = A + (size_t)(bm * 128 + srow) * K + schunk;
    const u16* Bg = Bt + (size_t)(bn * 128 + srow) * K + schunk;
    f32x4 acc[4][4] = {};
    for (int k0 = 0; k0 < K; k0 += 32) {
        u16x8 a0 = *(const u16x8*)(Ag + k0);
        u16x8 a1 = *(const u16x8*)(Ag + (size_t)64 * K + k0);
        u16x8 b0 = *(const u16x8*)(Bg + k0);
        u16x8 b1 = *(const u16x8*)(Bg + (size_t)64 * K + k0);
        __syncthreads();
        *(u16x8*)&As[srow * 40 + schunk] = a0;
        *(u16x8*)&As[(srow + 64) * 40 + schunk] = a1;
        *(u16x8*)&Bs[srow * 40 + schunk] = b0;
        *(u16x8*)&Bs[(srow + 64) * 40 + schunk] = b1;
        __syncthreads();
        bf16x8 af[4], bf[4];
#pragma unroll
        for (int mi = 0; mi < 4; mi++)
            af[mi] = __builtin_bit_cast(bf16x8, *(const u16x8*)&As[(wm * 64 + mi * 16 + l15) * 40 + lg * 8]);
#pragma unroll
        for (int ni = 0; ni < 4; ni++)
            bf[ni] = __builtin_bit_cast(bf16x8, *(const u16x8*)&Bs[(wn * 64 + ni * 16 + l15) * 40 + lg * 8]);
#pragma unroll
        for (int mi = 0; mi < 4; mi++)
#pragma unroll
            for (int ni = 0; ni < 4; ni++)
                acc[mi][ni] = __builtin_amdgcn_mfma_f32_16x16x32_bf16(af[mi], bf[ni], acc[mi][ni], 0, 0, 0);
    }
#pragma unroll
    for (int mi = 0; mi < 4; mi++) {
        int gr0 = bm * 128 + wm * 64 + mi * 16 + lg * 4;
#pragma unroll
        for (int ni = 0; ni < 4; ni++) {
            int gc = bn * 128 + wn * 64 + ni * 16 + l15;
#pragma unroll
            for (int r = 0; r < 4; r++) {
                if (OUT_BF16)
                    ((u16*)Cv)[(size_t)(gr0 + r) * ldc + gc] = f2bf(acc[mi][ni][r]);
                else
                    ((float*)Cv)[(size_t)(gr0 + r) * ldc + gc] = acc[mi][ni][r];
            }
        }
    }
}

// ---------------- ba = hidden @ W_ba (fp32, N=64) ----------------
__global__ void k_ba(const float* __restrict__ hid, const float* __restrict__ Wba, float* __restrict__ ba) {
    int token = blockIdx.x;
    int c = threadIdx.x;  // 64
    const float* h = hid + (size_t)token * HID;
    const float* w = Wba + c;
    float acc = 0.f;
    for (int k = 0; k < HID; k += 4) {
        float4 hv = *(const float4*)(h + k);
        acc += hv.x * w[(size_t)k * 64] + hv.y * w[(size_t)(k + 1) * 64] +
               hv.z * w[(size_t)(k + 2) * 64] + hv.w * w[(size_t)(k + 3) * 64];
    }
    ba[(size_t)token * 64 + c] = acc;
}

// ---------------- causal depthwise conv4 + silu + l2norm + {exp(g),beta} ----------------
// Writes scan-friendly layouts: qs/ks [b][hk][t][128], vs [b][hv][t][128], gb2 [b][hv][t] float2.
__global__ __launch_bounds__(256) void k_conv(const u16* __restrict__ qkvz, const float* __restrict__ ba,
                                              const float* __restrict__ cw, const float* __restrict__ A_log,
                                              const float* __restrict__ dt_bias, float* __restrict__ qs,
                                              float* __restrict__ ks, float* __restrict__ vs,
                                              float2* __restrict__ gb2) {
    __shared__ float sm[4096];
    int token = blockIdx.x;
    int b = token >> 10;
    int t = token & (S_ - 1);
    int tid = threadIdx.x;
    const u16* row3 = qkvz + (size_t)token * QKVZ_N;
#pragma unroll
    for (int i = 0; i < 32; i++) {
        int c = tid + i * 256;
        int col;
        if (c < 2048) col = (c >> 7) * 768 + (c & 127);
        else if (c < 4096) col = ((c - 2048) >> 7) * 768 + 128 + (c & 127);
        else {
            int cc = c - 4096;
            col = (cc >> 8) * 768 + 256 + ((cc >> 7) & 1) * 128 + (cc & 127);
        }
        float4 w = *(const float4*)(cw + c * 4);
        float x3 = bf2f(row3[col]);
        float x2 = (t >= 1) ? bf2f(row3[col - QKVZ_N]) : 0.f;
        float x1 = (t >= 2) ? bf2f(row3[col - 2 * QKVZ_N]) : 0.f;
        float x0 = (t >= 3) ? bf2f(row3[col - 3 * QKVZ_N]) : 0.f;
        float s = w.x * x0 + w.y * x1 + w.z * x2 + w.w * x3;
        s = s / (1.f + __expf(-s));  // silu
        if (c < 4096) sm[c] = s;
        else {
            int cc = c - 4096;
            int hv = cc >> 7, d = cc & 127;
            vs[((size_t)(b * NV + hv) * S_ + t) * 128 + d] = s;
        }
    }
    __syncthreads();
    int grp = tid >> 3, l8 = tid & 7;
    float vals[16];
    float ss = 0.f;
    const float* sp = sm + grp * 128 + l8 * 16;
#pragma unroll
    for (int i = 0; i < 16; i++) { vals[i] = sp[i]; ss += vals[i] * vals[i]; }
    ss += __shfl_xor(ss, 1); ss += __shfl_xor(ss, 2); ss += __shfl_xor(ss, 4);
    float scale = rsqrtf(ss + 1e-6f);
    if (grp < 16) scale *= 0.08838834764831845f;  // DK^-0.5
    float* op = (grp < 16 ? qs : ks) + ((size_t)(b * NK + (grp & 15)) * S_ + t) * 128 + l8 * 16;
#pragma unroll
    for (int i = 0; i < 16; i++) op[i] = vals[i] * scale;
    if (tid < 32) {
        int hv = tid;
        float bval = ba[(size_t)token * 64 + (hv >> 1) * 4 + (hv & 1)];
        float aval = ba[(size_t)token * 64 + (hv >> 1) * 4 + 2 + (hv & 1)];
        float x = aval + dt_bias[hv];
        float sp2 = (x > 20.f) ? x : log1pf(__expf(x));
        float eg = __expf(-__expf(A_log[hv]) * sp2);
        float bt = 1.f / (1.f + __expf(-bval));
        gb2[(size_t)(b * NV + hv) * S_ + t] = make_float2(eg, bt);
    }
}

// ---------------- sequential delta-rule scan ----------------
// grid = 64 (b,hv) * 4 v-splits; block = 512. 16-lane group per v-column,
// each lane owns 8 state rows. All scan inputs packed with 512B step stride ->
// immediate-offset loads within a 4-step unrolled window.
struct Ring { f32x8v k, q; f32x2 gb; float v; };

__device__ __forceinline__ void scan_step(const Ring& r, f32x2 st2[4], float* outp, bool writer) {
    f32x2 k0 = __builtin_shufflevector(r.k, r.k, 0, 1);
    f32x2 k1 = __builtin_shufflevector(r.k, r.k, 2, 3);
    f32x2 k2 = __builtin_shufflevector(r.k, r.k, 4, 5);
    f32x2 k3 = __builtin_shufflevector(r.k, r.k, 6, 7);
    f32x2 p0 = k0 * st2[0];
    p0 = __builtin_elementwise_fma(k1, st2[1], p0);
    f32x2 p1 = k2 * st2[2];
    p1 = __builtin_elementwise_fma(k3, st2[3], p1);
    f32x2 ps = p0 + p1;
    float dks = sum16(ps.x + ps.y);
    float eg = r.gb.x;
    float delta = (r.v - eg * dks) * r.gb.y;
    f32x2 e2 = {eg, eg}, d2 = {delta, delta};
    st2[0] = __builtin_elementwise_fma(st2[0], e2, k0 * d2);
    st2[1] = __builtin_elementwise_fma(st2[1], e2, k1 * d2);
    st2[2] = __builtin_elementwise_fma(st2[2], e2, k2 * d2);
    st2[3] = __builtin_elementwise_fma(st2[3], e2, k3 * d2);
    f32x2 q0 = __builtin_shufflevector(r.q, r.q, 0, 1);
    f32x2 q1 = __builtin_shufflevector(r.q, r.q, 2, 3);
    f32x2 q2 = __builtin_shufflevector(r.q, r.q, 4, 5);
    f32x2 q3 = __builtin_shufflevector(r.q, r.q, 6, 7);
    f32x2 o0 = q0 * st2[0];
    o0 = __builtin_elementwise_fma(q1, st2[1], o0);
    f32x2 o1 = q2 * st2[2];
    o1 = __builtin_elementwise_fma(q3, st2[3], o1);
    f32x2 os = o0 + o1;
    float dqs = sum16(os.x + os.y);
    if (writer) *outp = dqs;
}

__global__ __launch_bounds__(512) void k_scan(const float* __restrict__ qs, const float* __restrict__ ks,
                                              const float* __restrict__ vs, const float2* __restrict__ gb2,
                                              float* __restrict__ core) {
    int bid = blockIdx.x;
    int bh = bid >> 2, vsp = bid & 3;
    int b = bh >> 5, hv = bh & 31, hk = hv >> 1;
    int tid = threadIdx.x;
    int vloc = tid >> 4, rq = tid & 15;
    int vidx = vsp * 32 + vloc;
    const float* kp = ks + ((size_t)(b * NK + hk) * S_) * 128 + rq * 8;
    const float* qp = qs + ((size_t)(b * NK + hk) * S_) * 128 + rq * 8;
    const float* vp = vs + ((size_t)(b * NV + hv) * S_) * 128 + vidx;
    const f32x2* gp = (const f32x2*)(gb2 + (size_t)(b * NV + hv) * S_);
    float* cp = core + ((size_t)(b * NV + hv) * S_) * 128 + vidx;
    bool writer = (rq == 0);
    f32x2 st2[4] = {};
    Ring rg[4];
#pragma unroll
    for (int j = 0; j < 4; j++) {
        rg[j].k = *(const f32x8v*)(kp + j * 128);
        rg[j].q = *(const f32x8v*)(qp + j * 128);
        rg[j].v = vp[j * 128];
        rg[j].gb = gp[j];
    }
    for (int t0 = 0; t0 < S_ - 4; t0 += 4) {
#pragma unroll
        for (int j = 0; j < 4; j++) {
            Ring cur = rg[j];
            rg[j].k = *(const f32x8v*)(kp + (4 + j) * 128);
            rg[j].q = *(const f32x8v*)(qp + (4 + j) * 128);
            rg[j].v = vp[(4 + j) * 128];
            rg[j].gb = gp[4 + j];
            scan_step(cur, st2, cp + j * 128, writer);
        }
        kp += 512; qp += 512; vp += 512; gp += 4; cp += 512;
    }
#pragma unroll
    for (int j = 0; j < 4; j++)
        scan_step(rg[j], st2, cp + j * 128, writer);
}

// ---------------- RMS-norm * norm_weight * silu(z) -> bf16 ----------------
// core layout now [b][hv][t][128].
__global__ __launch_bounds__(256) void k_gate(const float* __restrict__ core, const u16* __restrict__ qkvz,
                                              const float* __restrict__ nw, u16* __restrict__ gated) {
    int token = blockIdx.x, tid = threadIdx.x;
    int b = token >> 10, t = token & (S_ - 1);
    int grp = tid >> 3, l8 = tid & 7;
    const float* cp = core + ((size_t)(b * NV + grp) * S_ + t) * DV_ + l8 * 16;
    float vals[16];
    float ss = 0.f;
#pragma unroll
    for (int i = 0; i < 16; i++) { vals[i] = cp[i]; ss += vals[i] * vals[i]; }
    ss += __shfl_xor(ss, 1); ss += __shfl_xor(ss, 2); ss += __shfl_xor(ss, 4);
    float rms = rsqrtf(ss * (1.0f / DV_) + 1e-6f);
    const u16* zp = qkvz + (size_t)token * QKVZ_N + (grp >> 1) * 768 + 512 + (grp & 1) * 128 + l8 * 16;
    u16* op = gated + ((size_t)token * NV + grp) * DV_ + l8 * 16;
#pragma unroll
    for (int i = 0; i < 16; i++) {
        float z = bf2f(zp[i]);
        float sz = z / (1.f + __expf(-z));
        op[i] = f2bf(vals[i] * rms * nw[l8 * 16 + i] * sz);
    }
}

extern "C" void kernel_launch(void* const* d_in, const int* in_sizes, int n_in,
                              void* d_out, int out_size, void* d_ws, size_t ws_size,
                              hipStream_t stream) {
    const float* hidden = (const float*)d_in[0];
    const float* Wqkvz = (const float*)d_in[1];
    const float* Wba = (const float*)d_in[2];
    const float* convw = (const float*)d_in[3];
    const float* A_log = (const float*)d_in[4];
    const float* dt_bias = (const float*)d_in[5];
    const float* norm_w = (const float*)d_in[6];
    const float* Wout = (const float*)d_in[7];

    char* ws = (char*)d_ws;
    size_t off = 0;
    auto alloc = [&](size_t bytes) -> void* {
        void* p = ws + off;
        off += (bytes + 255) & ~(size_t)255;
        return p;
    };
    u16* hiddenB = (u16*)alloc((size_t)TOK * HID * 2);
    u16* WqT = (u16*)alloc((size_t)QKVZ_N * HID * 2);
    u16* WoT = (u16*)alloc((size_t)HID * 4096 * 2);
    u16* qkvz = (u16*)alloc((size_t)TOK * QKVZ_N * 2);
    float* ba = (float*)alloc((size_t)TOK * 64 * 4);
    float* qs = (float*)alloc((size_t)B_ * NK * S_ * 128 * 4);
    float* ks = (float*)alloc((size_t)B_ * NK * S_ * 128 * 4);
    float* vs = (float*)alloc((size_t)B_ * NV * S_ * 128 * 4);
    float2* gb2 = (float2*)alloc((size_t)B_ * NV * S_ * 8);
    float* core = (float*)alloc((size_t)B_ * NV * S_ * 128 * 4);
    u16* gated = (u16*)alloc((size_t)TOK * 4096 * 2);

    k_cvt_bf16<<<4096, 256, 0, stream>>>(hidden, hiddenB, TOK * HID);
    k_transpose<<<dim3(QKVZ_N / 32, HID / 32), dim3(32, 8), 0, stream>>>(Wqkvz, WqT, HID, QKVZ_N);
    k_transpose<<<dim3(HID / 32, 4096 / 32), dim3(32, 8), 0, stream>>>(Wout, WoT, 4096, HID);
    k_gemm<1><<<dim3(QKVZ_N / 128, TOK / 128), 256, 0, stream>>>(hiddenB, WqT, qkvz, HID, QKVZ_N);
    k_ba<<<TOK, 64, 0, stream>>>(hidden, Wba, ba);
    k_conv<<<TOK, 256, 0, stream>>>(qkvz, ba, convw, A_log, dt_bias, qs, ks, vs, gb2);
    k_scan<<<256, 512, 0, stream>>>(qs, ks, vs, gb2, core);
    k_gate<<<TOK, 256, 0, stream>>>(core, qkvz, norm_w, gated);
    k_gemm<0><<<dim3(HID / 128, TOK / 128), 256, 0, stream>>>(gated, WoT, d_out, 4096, HID);
}

// Round 4
// 647.341 us; speedup vs baseline: 1.5871x; 1.1462x over previous
//
#include <hip/hip_runtime.h>
#include <stdint.h>

#define B_ 2
#define S_ 1024
#define HID 2048
#define NK 16
#define NV 32
#define DK_ 128
#define DV_ 128
#define QKVZ_N 12288
#define TOK (B_*S_)
#define KROW 144  // padded k/q row (words): group rq at word rq*8+(rq>>2)*4

typedef unsigned short u16;
typedef __bf16 bf16x8 __attribute__((ext_vector_type(8)));
typedef float f32x4 __attribute__((ext_vector_type(4)));
typedef float f32x2 __attribute__((ext_vector_type(2)));
typedef unsigned short u16x8 __attribute__((ext_vector_type(8)));
typedef unsigned short u16x4 __attribute__((ext_vector_type(4)));

__device__ __forceinline__ float bf2f(u16 u) {
    return __builtin_bit_cast(float, (unsigned)u << 16);
}
__device__ __forceinline__ u16 f2bf(float f) {
    unsigned u = __builtin_bit_cast(unsigned, f);
    u += 0x7fff + ((u >> 16) & 1);
    return (u16)(u >> 16);
}

// 16-lane butterfly sum via DPP (full-rate VALU, no LDS routing).
template <int CTRL>
__device__ __forceinline__ float dpp_add(float x) {
    int yi = __builtin_amdgcn_update_dpp(0, __builtin_bit_cast(int, x), CTRL, 0xF, 0xF, true);
    return x + __builtin_bit_cast(float, yi);
}
__device__ __forceinline__ float sum16(float x) {
    x = dpp_add<0xB1>(x);   // quad_perm xor1
    x = dpp_add<0x4E>(x);   // quad_perm xor2
    x = dpp_add<0x141>(x);  // row_half_mirror
    x = dpp_add<0x140>(x);  // row_mirror
    return x;
}

// async global -> LDS (width literal). LDS dest: wave-uniform base + lane*size.
__device__ __forceinline__ void gl16(const void* g, void* l) {
    __builtin_amdgcn_global_load_lds((const __attribute__((address_space(1))) uint32_t*)g,
                                     (__attribute__((address_space(3))) uint32_t*)l, 16, 0, 0);
}
__device__ __forceinline__ void gl4(const void* g, void* l) {
    __builtin_amdgcn_global_load_lds((const __attribute__((address_space(1))) uint32_t*)g,
                                     (__attribute__((address_space(3))) uint32_t*)l, 4, 0, 0);
}

// ---------------- fp32 -> bf16 elementwise ----------------
__global__ void k_cvt_bf16(const float* __restrict__ in, u16* __restrict__ out, int n) {
    int i = (blockIdx.x * blockDim.x + threadIdx.x) * 4;
    if (i >= n) return;
    float4 v = *(const float4*)(in + i);
    u16x4 o = { f2bf(v.x), f2bf(v.y), f2bf(v.z), f2bf(v.w) };
    *(u16x4*)(out + i) = o;
}

// ---------------- fp32 (R,C) -> bf16 (C,R) tiled transpose ----------------
__global__ void k_transpose(const float* __restrict__ in, u16* __restrict__ out, int R, int C) {
    __shared__ float tile[32][33];
    int c0 = blockIdx.x * 32, r0 = blockIdx.y * 32;
    int tx = threadIdx.x, ty = threadIdx.y;  // (32,8)
#pragma unroll
    for (int i = 0; i < 4; i++)
        tile[ty + i * 8][tx] = in[(size_t)(r0 + ty + i * 8) * C + c0 + tx];
    __syncthreads();
#pragma unroll
    for (int i = 0; i < 4; i++)
        out[(size_t)(c0 + ty + i * 8) * R + r0 + tx] = f2bf(tile[tx][ty + i * 8]);
}

// ---------------- bf16 GEMM: C(M,N) = A(M,K) * Bt(N,K)^T ----------------
template <int OUT_BF16>
__global__ __launch_bounds__(256) void k_gemm(const u16* __restrict__ A, const u16* __restrict__ Bt,
                                              void* __restrict__ Cv, int K, int ldc) {
    __shared__ u16 As[128 * 40];
    __shared__ u16 Bs[128 * 40];
    int tid = threadIdx.x;
    int bm = blockIdx.y, bn = blockIdx.x;
    int wid = tid >> 6, lane = tid & 63;
    int wm = wid >> 1, wn = wid & 1;
    int l15 = lane & 15, lg = lane >> 4;
    int srow = tid >> 2, schunk = (tid & 3) * 8;
    const u16* Ag = A + (size_t)(bm * 128 + srow) * K + schunk;
    const u16* Bg = Bt + (size_t)(bn * 128 + srow) * K + schunk;
    f32x4 acc[4][4] = {};
    for (int k0 = 0; k0 < K; k0 += 32) {
        u16x8 a0 = *(const u16x8*)(Ag + k0);
        u16x8 a1 = *(const u16x8*)(Ag + (size_t)64 * K + k0);
        u16x8 b0 = *(const u16x8*)(Bg + k0);
        u16x8 b1 = *(const u16x8*)(Bg + (size_t)64 * K + k0);
        __syncthreads();
        *(u16x8*)&As[srow * 40 + schunk] = a0;
        *(u16x8*)&As[(srow + 64) * 40 + schunk] = a1;
        *(u16x8*)&Bs[srow * 40 + schunk] = b0;
        *(u16x8*)&Bs[(srow + 64) * 40 + schunk] = b1;
        __syncthreads();
        bf16x8 af[4], bf[4];
#pragma unroll
        for (int mi = 0; mi < 4; mi++)
            af[mi] = __builtin_bit_cast(bf16x8, *(const u16x8*)&As[(wm * 64 + mi * 16 + l15) * 40 + lg * 8]);
#pragma unroll
        for (int ni = 0; ni < 4; ni++)
            bf[ni] = __builtin_bit_cast(bf16x8, *(const u16x8*)&Bs[(wn * 64 + ni * 16 + l15) * 40 + lg * 8]);
#pragma unroll
        for (int mi = 0; mi < 4; mi++)
#pragma unroll
            for (int ni = 0; ni < 4; ni++)
                acc[mi][ni] = __builtin_amdgcn_mfma_f32_16x16x32_bf16(af[mi], bf[ni], acc[mi][ni], 0, 0, 0);
    }
#pragma unroll
    for (int mi = 0; mi < 4; mi++) {
        int gr0 = bm * 128 + wm * 64 + mi * 16 + lg * 4;
#pragma unroll
        for (int ni = 0; ni < 4; ni++) {
            int gc = bn * 128 + wn * 64 + ni * 16 + l15;
#pragma unroll
            for (int r = 0; r < 4; r++) {
                if (OUT_BF16)
                    ((u16*)Cv)[(size_t)(gr0 + r) * ldc + gc] = f2bf(acc[mi][ni][r]);
                else
                    ((float*)Cv)[(size_t)(gr0 + r) * ldc + gc] = acc[mi][ni][r];
            }
        }
    }
}

// ---------------- ba = hidden @ W_ba (fp32, N=64) ----------------
__global__ void k_ba(const float* __restrict__ hid, const float* __restrict__ Wba, float* __restrict__ ba) {
    int token = blockIdx.x;
    int c = threadIdx.x;  // 64
    const float* h = hid + (size_t)token * HID;
    const float* w = Wba + c;
    float acc = 0.f;
    for (int k = 0; k < HID; k += 4) {
        float4 hv = *(const float4*)(h + k);
        acc += hv.x * w[(size_t)k * 64] + hv.y * w[(size_t)(k + 1) * 64] +
               hv.z * w[(size_t)(k + 2) * 64] + hv.w * w[(size_t)(k + 3) * 64];
    }
    ba[(size_t)token * 64 + c] = acc;
}

// ---------------- causal depthwise conv4 + silu + l2norm + {exp(g),beta} ----------------
// qs/ks written as [b][hk][t][KROW] skewed rows (group rq at word rq*8+(rq>>2)*4),
// vs [b][hv][t][128], gb2 [b][hv][t] float2 = {exp(g), beta}.
__global__ __launch_bounds__(256) void k_conv(const u16* __restrict__ qkvz, const float* __restrict__ ba,
                                              const float* __restrict__ cw, const float* __restrict__ A_log,
                                              const float* __restrict__ dt_bias, float* __restrict__ qs,
                                              float* __restrict__ ks, float* __restrict__ vs,
                                              float2* __restrict__ gb2) {
    __shared__ float sm[4096];
    int token = blockIdx.x;
    int b = token >> 10;
    int t = token & (S_ - 1);
    int tid = threadIdx.x;
    const u16* row3 = qkvz + (size_t)token * QKVZ_N;
#pragma unroll
    for (int i = 0; i < 32; i++) {
        int c = tid + i * 256;
        int col;
        if (c < 2048) col = (c >> 7) * 768 + (c & 127);
        else if (c < 4096) col = ((c - 2048) >> 7) * 768 + 128 + (c & 127);
        else {
            int cc = c - 4096;
            col = (cc >> 8) * 768 + 256 + ((cc >> 7) & 1) * 128 + (cc & 127);
        }
        float4 w = *(const float4*)(cw + c * 4);
        float x3 = bf2f(row3[col]);
        float x2 = (t >= 1) ? bf2f(row3[col - QKVZ_N]) : 0.f;
        float x1 = (t >= 2) ? bf2f(row3[col - 2 * QKVZ_N]) : 0.f;
        float x0 = (t >= 3) ? bf2f(row3[col - 3 * QKVZ_N]) : 0.f;
        float s = w.x * x0 + w.y * x1 + w.z * x2 + w.w * x3;
        s = s / (1.f + __expf(-s));  // silu
        if (c < 4096) sm[c] = s;
        else {
            int cc = c - 4096;
            int hv = cc >> 7, d = cc & 127;
            vs[((size_t)(b * NV + hv) * S_ + t) * 128 + d] = s;
        }
    }
    __syncthreads();
    int grp = tid >> 3, l8 = tid & 7;
    float vals[16];
    float ss = 0.f;
    const float* sp = sm + grp * 128 + l8 * 16;
#pragma unroll
    for (int i = 0; i < 16; i++) { vals[i] = sp[i]; ss += vals[i] * vals[i]; }
    ss += __shfl_xor(ss, 1); ss += __shfl_xor(ss, 2); ss += __shfl_xor(ss, 4);
    float scale = rsqrtf(ss + 1e-6f);
    if (grp < 16) scale *= 0.08838834764831845f;  // DK^-0.5
    // skewed row: this thread's 16 floats (groups 2*l8, 2*l8+1) start at word l8*16+(l8>>1)*4
    float* op = (grp < 16 ? qs : ks) + ((size_t)(b * NK + (grp & 15)) * S_ + t) * KROW
              + l8 * 16 + (l8 >> 1) * 4;
#pragma unroll
    for (int i = 0; i < 16; i++) op[i] = vals[i] * scale;
    if (tid < 32) {
        int hv = tid;
        float bval = ba[(size_t)token * 64 + (hv >> 1) * 4 + (hv & 1)];
        float aval = ba[(size_t)token * 64 + (hv >> 1) * 4 + 2 + (hv & 1)];
        float x = aval + dt_bias[hv];
        float sp2 = (x > 20.f) ? x : log1pf(__expf(x));
        float eg = __expf(-__expf(A_log[hv]) * sp2);
        float bt = 1.f / (1.f + __expf(-bval));
        gb2[(size_t)(b * NV + hv) * S_ + t] = make_float2(eg, bt);
    }
}

// ---------------- sequential delta-rule scan, LDS double-buffered ----------------
// grid = 64 (b,hv) * 4 v-splits; block = 512 (8 waves). 16-lane group per v-column,
// each lane owns 8 state rows. Tiles of 32 steps staged async into LDS one tile ahead.
__global__ __launch_bounds__(512) void k_scan(const float* __restrict__ qs, const float* __restrict__ ks,
                                              const float* __restrict__ vs, const float2* __restrict__ gb2,
                                              float* __restrict__ core) {
    __shared__ float kb[2][32 * KROW];
    __shared__ float qb[2][32 * KROW];
    __shared__ float vbf[2][32 * 32];
    __shared__ float2 gbl[2][32];
    int bid = blockIdx.x;
    int bh = bid >> 2, vsp = bid & 3;
    int b = bh >> 5, hv = bh & 31, hk = hv >> 1;
    int tid = threadIdx.x;
    int wid = tid >> 6, lane = tid & 63;
    int vloc = tid >> 4, rq = tid & 15;
    const char* kgb = (const char*)(ks + (size_t)(b * NK + hk) * S_ * KROW);
    const char* qgb = (const char*)(qs + (size_t)(b * NK + hk) * S_ * KROW);
    const char* vgb = (const char*)(vs + ((size_t)(b * NV + hv) * S_) * 128 + vsp * 32);
    const char* ggb = (const char*)(gb2 + (size_t)(b * NV + hv) * S_);
    float* cp = core + ((size_t)(b * NV + hv) * S_) * 128 + vsp * 32 + vloc;
    bool writer = (rq == 0);
    int koff = rq * 8 + (rq >> 2) * 4;  // skewed word offset within KROW row

    auto stage = [&](int tile, int buf) {
        const char* kg = kgb + (size_t)tile * 32 * (KROW * 4);
        const char* qg = qgb + (size_t)tile * 32 * (KROW * 4);
        const char* vg = vgb + (size_t)tile * 32 * 512;
        const char* gg = ggb + (size_t)tile * 32 * 8;
        // 18 KB k + 18 KB q + 4 KB v + 256 B gb = 41 chunks over 8 waves
        for (int ch = wid; ch < 41; ch += 8) {
            if (ch < 18)
                gl16(kg + ch * 1024 + lane * 16, (char*)&kb[buf][0] + ch * 1024);
            else if (ch < 36)
                gl16(qg + (ch - 18) * 1024 + lane * 16, (char*)&qb[buf][0] + (ch - 18) * 1024);
            else if (ch < 40) {
                int c4 = ch - 36;  // 1 KB = 8 t-rows x 32 cols
                gl16(vg + (size_t)(c4 * 8 + (lane >> 3)) * 512 + (lane & 7) * 16,
                     (char*)&vbf[buf][0] + c4 * 1024);
            } else
                gl4(gg + lane * 4, (char*)&gbl[buf][0]);
        }
    };

    f32x2 st2[4] = {};
    stage(0, 0);
    __syncthreads();  // drains vmcnt(0) -> tile 0 resident
    for (int tile = 0; tile < 32; ++tile) {
        int buf = tile & 1;
        if (tile < 31) stage(tile + 1, buf ^ 1);
        const float* kT = &kb[buf][0];
        const float* qT = &qb[buf][0];
        const float* vT = &vbf[buf][0];
        const float2* gT = &gbl[buf][0];
#pragma unroll
        for (int t = 0; t < 32; ++t) {
            f32x4 kA = *(const f32x4*)(kT + t * KROW + koff);
            f32x4 kB = *(const f32x4*)(kT + t * KROW + koff + 4);
            f32x4 qA = *(const f32x4*)(qT + t * KROW + koff);
            f32x4 qB = *(const f32x4*)(qT + t * KROW + koff + 4);
            float vv = vT[t * 32 + vloc];
            float2 gv = gT[t];
            f32x2 k0 = __builtin_shufflevector(kA, kA, 0, 1);
            f32x2 k1 = __builtin_shufflevector(kA, kA, 2, 3);
            f32x2 k2 = __builtin_shufflevector(kB, kB, 0, 1);
            f32x2 k3 = __builtin_shufflevector(kB, kB, 2, 3);
            f32x2 p0 = k0 * st2[0];
            p0 = __builtin_elementwise_fma(k1, st2[1], p0);
            f32x2 p1 = k2 * st2[2];
            p1 = __builtin_elementwise_fma(k3, st2[3], p1);
            f32x2 ps = p0 + p1;
            float dks = sum16(ps.x + ps.y);
            float eg = gv.x;
            float delta = (vv - eg * dks) * gv.y;
            f32x2 e2 = {eg, eg}, d2 = {delta, delta};
            st2[0] = __builtin_elementwise_fma(st2[0], e2, k0 * d2);
            st2[1] = __builtin_elementwise_fma(st2[1], e2, k1 * d2);
            st2[2] = __builtin_elementwise_fma(st2[2], e2, k2 * d2);
            st2[3] = __builtin_elementwise_fma(st2[3], e2, k3 * d2);
            f32x2 q0 = __builtin_shufflevector(qA, qA, 0, 1);
            f32x2 q1 = __builtin_shufflevector(qA, qA, 2, 3);
            f32x2 q2 = __builtin_shufflevector(qB, qB, 0, 1);
            f32x2 q3 = __builtin_shufflevector(qB, qB, 2, 3);
            f32x2 o0 = q0 * st2[0];
            o0 = __builtin_elementwise_fma(q1, st2[1], o0);
            f32x2 o1 = q2 * st2[2];
            o1 = __builtin_elementwise_fma(q3, st2[3], o1);
            f32x2 os = o0 + o1;
            float dqs = sum16(os.x + os.y);
            if (writer) cp[(size_t)(tile * 32 + t) * 128] = dqs;
        }
        __syncthreads();  // drains vmcnt -> next tile resident; buffers safe to reuse
    }
}

// ---------------- RMS-norm * norm_weight * silu(z) -> bf16 ----------------
__global__ __launch_bounds__(256) void k_gate(const float* __restrict__ core, const u16* __restrict__ qkvz,
                                              const float* __restrict__ nw, u16* __restrict__ gated) {
    int token = blockIdx.x, tid = threadIdx.x;
    int b = token >> 10, t = token & (S_ - 1);
    int grp = tid >> 3, l8 = tid & 7;
    const float* cp = core + ((size_t)(b * NV + grp) * S_ + t) * DV_ + l8 * 16;
    float vals[16];
    float ss = 0.f;
#pragma unroll
    for (int i = 0; i < 16; i++) { vals[i] = cp[i]; ss += vals[i] * vals[i]; }
    ss += __shfl_xor(ss, 1); ss += __shfl_xor(ss, 2); ss += __shfl_xor(ss, 4);
    float rms = rsqrtf(ss * (1.0f / DV_) + 1e-6f);
    const u16* zp = qkvz + (size_t)token * QKVZ_N + (grp >> 1) * 768 + 512 + (grp & 1) * 128 + l8 * 16;
    u16* op = gated + ((size_t)token * NV + grp) * DV_ + l8 * 16;
#pragma unroll
    for (int i = 0; i < 16; i++) {
        float z = bf2f(zp[i]);
        float sz = z / (1.f + __expf(-z));
        op[i] = f2bf(vals[i] * rms * nw[l8 * 16 + i] * sz);
    }
}

extern "C" void kernel_launch(void* const* d_in, const int* in_sizes, int n_in,
                              void* d_out, int out_size, void* d_ws, size_t ws_size,
                              hipStream_t stream) {
    const float* hidden = (const float*)d_in[0];
    const float* Wqkvz = (const float*)d_in[1];
    const float* Wba = (const float*)d_in[2];
    const float* convw = (const float*)d_in[3];
    const float* A_log = (const float*)d_in[4];
    const float* dt_bias = (const float*)d_in[5];
    const float* norm_w = (const float*)d_in[6];
    const float* Wout = (const float*)d_in[7];

    char* ws = (char*)d_ws;
    size_t off = 0;
    auto alloc = [&](size_t bytes) -> void* {
        void* p = ws + off;
        off += (bytes + 255) & ~(size_t)255;
        return p;
    };
    u16* hiddenB = (u16*)alloc((size_t)TOK * HID * 2);
    u16* WqT = (u16*)alloc((size_t)QKVZ_N * HID * 2);
    u16* WoT = (u16*)alloc((size_t)HID * 4096 * 2);
    u16* qkvz = (u16*)alloc((size_t)TOK * QKVZ_N * 2);
    float* ba = (float*)alloc((size_t)TOK * 64 * 4);
    float* qs = (float*)alloc((size_t)B_ * NK * S_ * KROW * 4);
    float* ks = (float*)alloc((size_t)B_ * NK * S_ * KROW * 4);
    float* vs = (float*)alloc((size_t)B_ * NV * S_ * 128 * 4);
    float2* gb2 = (float2*)alloc((size_t)B_ * NV * S_ * 8);
    float* core = (float*)alloc((size_t)B_ * NV * S_ * 128 * 4);
    u16* gated = (u16*)alloc((size_t)TOK * 4096 * 2);

    k_cvt_bf16<<<4096, 256, 0, stream>>>(hidden, hiddenB, TOK * HID);
    k_transpose<<<dim3(QKVZ_N / 32, HID / 32), dim3(32, 8), 0, stream>>>(Wqkvz, WqT, HID, QKVZ_N);
    k_transpose<<<dim3(HID / 32, 4096 / 32), dim3(32, 8), 0, stream>>>(Wout, WoT, 4096, HID);
    k_gemm<1><<<dim3(QKVZ_N / 128, TOK / 128), 256, 0, stream>>>(hiddenB, WqT, qkvz, HID, QKVZ_N);
    k_ba<<<TOK, 64, 0, stream>>>(hidden, Wba, ba);
    k_conv<<<TOK, 256, 0, stream>>>(qkvz, ba, convw, A_log, dt_bias, qs, ks, vs, gb2);
    k_scan<<<256, 512, 0, stream>>>(qs, ks, vs, gb2, core);
    k_gate<<<TOK, 256, 0, stream>>>(core, qkvz, norm_w, gated);
    k_gemm<0><<<dim3(HID / 128, TOK / 128), 256, 0, stream>>>(gated, WoT, d_out, 4096, HID);
}